// Round 5
// baseline (394.697 us; speedup 1.0000x reference)
//
#include <hip/hip_runtime.h>
#include <hip/hip_bf16.h>

// GCN encoder: out = concat(h1, h2), h_l = relu(Dinv(A+I)Dinv (x@W_l) + b_l)
// Inputs: x[N,128], W1,W2[128,128], b1,b2[128] = float32; edge_index int32 [2,E]
// Output: float32 [N,256] (harness compares vs bf16-emulated np ref, 2% rel).
//
// Round 10: ledger closed by round-9 probe: top-5 = harness 400MB fill (~60us,
// uncontrollable, 8 reset dispatches/iter interleaved with our 9); every
// non-agg kernel of ours < 59us. Changes this round:
//  1. agg un-split (back to 1 dispatch/layer; probe done, -2 dispatches).
//  2. gemm_scale epilogue: was 32 scalar 2B global stores/thread in 32B
//     segments (12.8M stores, ~2x write amplification on G). Now: scale+cvt
//     into padded LDS tile [64][136] bf16 (17.4KB), barrier, then 4 coalesced
//     bf16x8 stores/thread (1KB contiguous per wave-instruction).
// All else identical to round 9 (NT A-loads in gemm stay reverted).
//
// ws layout (bytes):
#define OFF_GCNT 0x0000000   // int[196]     bucket cursors (zeroed by prep_k)
#define OFF_RP   0x0001000   // int[N+1]     CSR row pointers
#define OFF_DINV 0x0070000   // float[N]     rsqrt(deg+1)
#define OFF_WT1  0x00E0000   // bf16[128*128] W1^T
#define OFF_WT2  0x00E8000   // bf16[128*128] W2^T
#define OFF_COL  0x00F0000   // int[E]       CSR col (src) ids
#define OFF_G    0x0710000   // overlay: gBuf (9.6MB, dead after build_k) then
                             //          bf16 G[N*128] (25.6MB)
#define OFF_H1   0x1F80000   // bf16[N*128]  h1 staged for layer-2 GEMM
#define WS_NEED  0x3800000   // ~58.7MB if H1 used; 33MB min otherwise

#define CAPL   64      // LDS slots per bucket in bin_k
#define MAXNBK 200     // static LDS sizing (actual NBK=196 for N=100000)
#define CAP2   12288   // global slots per bucket (avg fill 8163, +45 sigma)

typedef short bf16x8 __attribute__((ext_vector_type(8)));
typedef float f32x4 __attribute__((ext_vector_type(4)));
typedef float f32x2 __attribute__((ext_vector_type(2)));
typedef unsigned int u32x4 __attribute__((ext_vector_type(4)));

static __device__ __forceinline__ unsigned short f2bf(float f) {
    unsigned int u = __float_as_uint(f);
    u = u + 0x7fffu + ((u >> 16) & 1u);   // round-to-nearest-even
    return (unsigned short)(u >> 16);
}

// ---------- phase 0: zero gCnt + transpose/cvt W1,W2 (one dispatch) ----------
__global__ __launch_bounds__(256) void prep_k(
    const float* __restrict__ W1, const float* __restrict__ W2,
    unsigned short* __restrict__ WT1, unsigned short* __restrict__ WT2,
    int* __restrict__ gCnt, int NBK) {
    int idx = blockIdx.x * 256 + threadIdx.x;   // grid 64 -> 16384
    int n = idx >> 7, k = idx & 127;
    WT1[idx] = f2bf(W1[k * 128 + n]);
    WT2[idx] = f2bf(W2[k * 128 + n]);
    if (blockIdx.x == 0 && threadIdx.x < NBK) gCnt[threadIdx.x] = 0;
}

// ---------- phase 1: LDS-binned edge bucketing ----------
__global__ __launch_bounds__(256) void bin_k(
    const int* __restrict__ src, const int* __restrict__ dst,
    int* __restrict__ gCnt, unsigned* __restrict__ gBuf, int E, int NBK) {
    __shared__ int lcnt[MAXNBK];
    __shared__ unsigned lbuf[MAXNBK * CAPL];
    for (int i = threadIdx.x; i < NBK; i += 256) lcnt[i] = 0;
    __syncthreads();
    int base = blockIdx.x * 4096;
#pragma unroll 4
    for (int j = 0; j < 16; j++) {
        int e = base + j * 256 + threadIdx.x;
        if (e < E) {
            int d = dst[e], s = src[e];
            int b = d >> 9;
            unsigned entry = ((unsigned)(d & 511) << 23) | (unsigned)s;
            int pos = atomicAdd(&lcnt[b], 1);
            if (pos < CAPL) {
                lbuf[b * CAPL + pos] = entry;
            } else {            // overflow spill (statistically never at CAPL=64)
                int gp = atomicAdd(&gCnt[b], 1);
                if (gp < CAP2) gBuf[(size_t)b * CAP2 + gp] = entry;
            }
        }
    }
    __syncthreads();
    for (int b = threadIdx.x; b < NBK; b += 256) {
        int n = lcnt[b]; if (n > CAPL) n = CAPL;
        if (n) {
            int gp = atomicAdd(&gCnt[b], n);
            for (int k = 0; k < n; k++) {
                int p = gp + k;
                if (p < CAP2) gBuf[(size_t)b * CAP2 + p] = lbuf[b * CAPL + k];
            }
        }
    }
}

// ---------- phase 2: per-bucket counting sort -> rp, dinv, col ----------
__global__ __launch_bounds__(256) void build_k(
    const unsigned* __restrict__ gBuf, const int* __restrict__ gCnt,
    int* __restrict__ rp, float* __restrict__ dinv, int* __restrict__ col,
    int NBK, int N) {
    __shared__ unsigned entries[CAP2];
    __shared__ int bc[256], tmp[256];
    __shared__ int ncnt[512], nrp[512], ncur[512];
    int t = threadIdx.x, b = blockIdx.x;

    // scan bucket counts -> colBase
    int c = (t < NBK) ? gCnt[t] : 0;
    if (c > CAP2) c = CAP2;
    bc[t] = c;
    tmp[t] = c;
    __syncthreads();
    for (int off = 1; off < 256; off <<= 1) {
        int x = (t >= off) ? tmp[t - off] : 0;
        __syncthreads(); tmp[t] += x; __syncthreads();
    }
    int colBase = tmp[b] - bc[b];
    int total = tmp[255];
    int cntb = bc[b];
    if (b == 0 && t == 0) rp[N] = total;

    // load this bucket's entries
    for (int k = t; k < cntb; k += 256) entries[k] = gBuf[(size_t)b * CAP2 + k];
    ncnt[t] = 0; ncnt[t + 256] = 0;
    __syncthreads();

    // pass A: per-node counts
    for (int k = t; k < cntb; k += 256) atomicAdd(&ncnt[entries[k] >> 23], 1);
    __syncthreads();

    // exclusive scan of 512 counts with 256 threads
    int v0 = ncnt[2 * t], v1 = ncnt[2 * t + 1];
    int ps = v0 + v1;
    tmp[t] = ps;
    __syncthreads();
    for (int off = 1; off < 256; off <<= 1) {
        int x = (t >= off) ? tmp[t - off] : 0;
        __syncthreads(); tmp[t] += x; __syncthreads();
    }
    int ex = tmp[t] - ps;
    nrp[2 * t] = ex;          ncur[2 * t] = ex;
    nrp[2 * t + 1] = ex + v0; ncur[2 * t + 1] = ex + v0;
    __syncthreads();

    // rp + dinv (coalesced)
    int g0 = b << 9;
    for (int i = t; i < 512; i += 256) {
        int g = g0 + i;
        if (g < N) {
            rp[g] = colBase + nrp[i];
            dinv[g] = rsqrtf((float)(ncnt[i] + 1));
        }
    }
    __syncthreads();

    // pass B: place into col (scatter confined to this bucket's region)
    for (int k = t; k < cntb; k += 256) {
        unsigned e = entries[k];
        int dl = e >> 23;
        int s = (int)(e & 0x7fffffu);
        int pos = atomicAdd(&ncur[dl], 1);
        col[colBase + pos] = s;
    }
}

// ---------- GEMM: G[r,:] = bf16( (A[r,:] @ W) * dinv[r] ) ----------
// AF32=1: A is float32 [M,lda]; AF32=0: A is bf16 (ushort) [M,lda]
// Epilogue: scale+cvt into padded LDS [64][136] bf16 (16B-aligned rows, quad
// bank-stagger), then coalesced bf16x8 stores (1KB per wave-instruction).
template <int AF32>
__global__ __launch_bounds__(256) void gemm_scale(
    const void* __restrict__ Av, int lda,
    const unsigned short* __restrict__ WT,
    const float* __restrict__ dinv,
    unsigned short* __restrict__ G, int M) {
    __shared__ unsigned short ge[64][136];   // 17.4KB
    int wave = threadIdx.x >> 6;
    int lane = threadIdx.x & 63;
    int quad = lane >> 4;
    int l16  = lane & 15;
    int rowBase = blockIdx.x * 64 + wave * 16;
    int rowc = rowBase + l16;
    if (rowc > M - 1) rowc = M - 1;

    f32x4 acc[8];
#pragma unroll
    for (int t = 0; t < 8; t++) acc[t] = (f32x4){0.f, 0.f, 0.f, 0.f};

#pragma unroll
    for (int kk = 0; kk < 128; kk += 32) {
        bf16x8 a;
        if (AF32) {
            const float* Af = (const float*)Av;
            const f32x4* ap = (const f32x4*)(Af + (size_t)rowc * lda + kk + quad * 8);
            f32x4 a0 = ap[0], a1 = ap[1];
#pragma unroll
            for (int j = 0; j < 4; j++) {
                a[j]     = (short)f2bf(a0[j]);
                a[j + 4] = (short)f2bf(a1[j]);
            }
        } else {
            const unsigned short* Ab = (const unsigned short*)Av;
            a = *(const bf16x8*)(Ab + (size_t)rowc * lda + kk + quad * 8);
        }
#pragma unroll
        for (int t = 0; t < 8; t++) {
            bf16x8 b = *(const bf16x8*)(WT + (t * 16 + l16) * 128 + kk + quad * 8);
            acc[t] = __builtin_amdgcn_mfma_f32_16x16x32_bf16(a, b, acc[t], 0, 0, 0);
        }
    }
    // D layout: row = quad*4 + reg, col = l16 (within each 16x16 tile t).
    // Stage into LDS (scale+cvt), rows clamped; garbage rows never stored.
    int lrow0 = wave * 16 + quad * 4;
#pragma unroll
    for (int r = 0; r < 4; r++) {
        int orow = rowBase + quad * 4 + r;
        float di = dinv[(orow < M) ? orow : (M - 1)];
#pragma unroll
        for (int t = 0; t < 8; t++) {
            ge[lrow0 + r][t * 16 + l16] = f2bf(acc[t][r] * di);
        }
    }
    __syncthreads();
    // coalesced store: per rep, 256 threads cover 16 rows x 128ch in bf16x8
    int mrow = M - blockIdx.x * 64;          // valid rows in this block
    int ch = (threadIdx.x & 15) * 8;
#pragma unroll
    for (int rep = 0; rep < 4; rep++) {
        int row = rep * 16 + (threadIdx.x >> 4);
        if (row < mrow) {
            bf16x8 v = *(const bf16x8*)&ge[row][ch];
            *(bf16x8*)(G + (size_t)(blockIdx.x * 64 + row) * 128 + ch) = v;
        }
    }
}

// ---------- Aggregate ----------
// out[n,:] = relu(dinv[n]*(g[n,:] + sum_{s in N(n)} g[s,:]) + b)
// One wave per node. lane = 16*g + i: group g processes edge slots g, g+4,
// g+8,... (slot e0-1 = self-loop); lane loads channels [8i, 8i+8) as 16B.
// Four slots in flight per group; invalid slots clamp to the self row and
// their accumulate is predicated off. NT stores for Out/H.
static __device__ __forceinline__ void accum8(f32x2* acc, u32x4 v) {
#pragma unroll
    for (int d = 0; d < 4; d++) {
        f32x2 t;
        t[0] = __uint_as_float(v[d] << 16);
        t[1] = __uint_as_float(v[d] & 0xffff0000u);
        acc[d] += t;                       // v_pk_add_f32
    }
}

__global__ __launch_bounds__(256) void agg_k(
    const unsigned short* __restrict__ G,
    const int* __restrict__ rp, const int* __restrict__ col,
    const float* __restrict__ dinv, const float* __restrict__ bias,
    float* __restrict__ Out, unsigned short* __restrict__ H,
    int colbase, int N) {
    int gid = (blockIdx.x * blockDim.x + threadIdx.x) >> 6;
    if (gid >= N) return;
    int lane = threadIdx.x & 63;
    int g = lane >> 4, i = lane & 15;

    f32x2 acc[4];
#pragma unroll
    for (int j = 0; j < 4; j++) acc[j] = (f32x2){0.f, 0.f};

    int e0 = rp[gid], e1 = rp[gid + 1];
    // virtual slot list: index e0-1 == self, then col[e0..e1).
    // group g owns slots e0-1+g, +4, +8, ... ; window of 4 in flight.
    int my = e0 - 1 + g;
    int c0 = (my < e1) ? ((my >= e0) ? __builtin_nontemporal_load(col + my) : gid)
                       : -1; my += 4;
    int c1 = (my < e1) ? __builtin_nontemporal_load(col + my) : -1; my += 4;
    int c2 = (my < e1) ? __builtin_nontemporal_load(col + my) : -1; my += 4;
    int c3 = (my < e1) ? __builtin_nontemporal_load(col + my) : -1; my += 4;

    const unsigned short* Gi = G + (size_t)i * 8;

    while (c0 >= 0) {
        int n0 = (my < e1) ? __builtin_nontemporal_load(col + my) : -1; my += 4;
        int n1 = (my < e1) ? __builtin_nontemporal_load(col + my) : -1; my += 4;
        int n2 = (my < e1) ? __builtin_nontemporal_load(col + my) : -1; my += 4;
        int n3 = (my < e1) ? __builtin_nontemporal_load(col + my) : -1; my += 4;
        int a1 = (c1 >= 0) ? c1 : gid;
        int a2 = (c2 >= 0) ? c2 : gid;
        int a3 = (c3 >= 0) ? c3 : gid;
        u32x4 v0 = *(const u32x4*)(Gi + (size_t)c0 * 128);
        u32x4 v1 = *(const u32x4*)(Gi + (size_t)a1 * 128);
        u32x4 v2 = *(const u32x4*)(Gi + (size_t)a2 * 128);
        u32x4 v3 = *(const u32x4*)(Gi + (size_t)a3 * 128);
        accum8(acc, v0);
        if (c1 >= 0) accum8(acc, v1);
        if (c2 >= 0) accum8(acc, v2);
        if (c3 >= 0) accum8(acc, v3);
        c0 = n0; c1 = n1; c2 = n2; c3 = n3;
    }

    float a8[8];
#pragma unroll
    for (int d = 0; d < 4; d++) { a8[2 * d] = acc[d][0]; a8[2 * d + 1] = acc[d][1]; }
#pragma unroll
    for (int j = 0; j < 8; j++) a8[j] += __shfl_xor(a8[j], 16, 64);
#pragma unroll
    for (int j = 0; j < 8; j++) a8[j] += __shfl_xor(a8[j], 32, 64);

    if (g == 0) {
        float di = dinv[gid];
        const f32x4* bp = (const f32x4*)(bias + i * 8);
        f32x4 b0 = bp[0], b1 = bp[1];
        f32x4 o0, o1;
#pragma unroll
        for (int j = 0; j < 4; j++) {
            o0[j] = fmaxf(a8[j] * di + b0[j], 0.f);
            o1[j] = fmaxf(a8[j + 4] * di + b1[j], 0.f);
        }
        float* orow = Out + (size_t)gid * 256 + colbase + i * 8;
        __builtin_nontemporal_store(o0, (f32x4*)orow);
        __builtin_nontemporal_store(o1, (f32x4*)(orow + 4));
        if (H) {
            bf16x8 hv;
#pragma unroll
            for (int j = 0; j < 4; j++) {
                hv[j]     = (short)f2bf(o0[j]);
                hv[j + 4] = (short)f2bf(o1[j]);
            }
            __builtin_nontemporal_store(hv, (bf16x8*)(H + (size_t)gid * 128 + i * 8));
        }
    }
}

extern "C" void kernel_launch(void* const* d_in, const int* in_sizes, int n_in,
                              void* d_out, int out_size, void* d_ws, size_t ws_size,
                              hipStream_t stream) {
    const float* x  = (const float*)d_in[0];   // [N,128] f32
    const float* W1 = (const float*)d_in[1];   // [128,128] f32
    const float* b1 = (const float*)d_in[2];   // [128] f32
    const float* W2 = (const float*)d_in[3];
    const float* b2 = (const float*)d_in[4];
    const int* ei = (const int*)d_in[5];       // [2,E] int32

    const int N = in_sizes[0] / 128;
    const int E = in_sizes[5] / 2;
    const int* src = ei;
    const int* dst = ei + E;
    const int NBK = (N + 511) >> 9;            // 196 for N=100000 (<= MAXNBK)

    char* ws = (char*)d_ws;
    int*      gCnt = (int*)(ws + OFF_GCNT);
    int*      rp   = (int*)(ws + OFF_RP);
    float*    dinv = (float*)(ws + OFF_DINV);
    unsigned short* WT1 = (unsigned short*)(ws + OFF_WT1);
    unsigned short* WT2 = (unsigned short*)(ws + OFF_WT2);
    int*      col  = (int*)(ws + OFF_COL);
    unsigned* gBuf = (unsigned*)(ws + OFF_G);          // dead after build_k
    unsigned short* G = (unsigned short*)(ws + OFF_G); // overlays gBuf
    unsigned short* H1 = (ws_size >= (size_t)WS_NEED)
                         ? (unsigned short*)(ws + OFF_H1) : nullptr;
    float* out = (float*)d_out;

    prep_k<<<64, 256, 0, stream>>>(W1, W2, WT1, WT2, gCnt, NBK);
    bin_k<<<(E + 4095) / 4096, 256, 0, stream>>>(src, dst, gCnt, gBuf, E, NBK);
    build_k<<<NBK, 256, 0, stream>>>(gBuf, gCnt, rp, dinv, col, NBK, N);

    int gb = (N + 63) / 64;
    int ab = (N + 3) / 4;

    // Layer 1 (A = x, f32)
    gemm_scale<1><<<gb, 256, 0, stream>>>(x, 128, WT1, dinv, G, N);
    agg_k<<<ab, 256, 0, stream>>>(G, rp, col, dinv, b1, out, H1, 0, N);
    // Layer 2 (A = h1: bf16 H1 if scratch allows, else f32 rows of out)
    if (H1) {
        gemm_scale<0><<<gb, 256, 0, stream>>>(H1, 128, WT2, dinv, G, N);
    } else {
        gemm_scale<1><<<gb, 256, 0, stream>>>(out, 256, WT2, dinv, G, N);
    }
    agg_k<<<ab, 256, 0, stream>>>(G, rp, col, dinv, b2, out, nullptr, 128, N);
}

// Round 6
// 377.546 us; speedup vs baseline: 1.0454x; 1.0454x over previous
//
#include <hip/hip_runtime.h>
#include <hip/hip_bf16.h>

// GCN encoder: out = concat(h1, h2), h_l = relu(Dinv(A+I)Dinv (x@W_l) + b_l)
// Inputs: x[N,128], W1,W2[128,128], b1,b2[128] = float32; edge_index int32 [2,E]
// Output: float32 [N,256] (harness compares vs bf16-emulated np ref, 2% rel).
//
// Round 11: assemble the empirically-best variant + cut bytes from the
// saturated kernel.
//  - gemm: revert to round-9 body (plain A loads, scalar G stores). The LDS
//    epilogue (round 10) measured +12us: barrier+LDS round trip serialized a
//    store tail that scalar stores hid under MFMA latency.
//  - H1 dropped: out[:,0:128] f32 IS relu(h1); gemm2 reads A from out
//    (lda=256, f2bf gives bit-identical bf16 to the old H1 staging). This
//    moves 25.6MB of writes out of agg1 -- the kernel measured at 7.4 TB/s
//    combined delivered R+W (above the 6.3 streaming ceiling, L2-assisted) --
//    into gemm2 reads, which is far below ceiling.
//  - bin_k: int4 edge loads (4 edges/lane, 16B) halves its stream-load count.
// agg remains 4-deep/NT (round-6 win). 7 dispatches.
//
// ws layout (bytes):
#define OFF_GCNT 0x0000000   // int[196]     bucket cursors (zeroed by prep_k)
#define OFF_RP   0x0001000   // int[N+1]     CSR row pointers
#define OFF_DINV 0x0070000   // float[N]     rsqrt(deg+1)
#define OFF_WT1  0x00E0000   // bf16[128*128] W1^T
#define OFF_WT2  0x00E8000   // bf16[128*128] W2^T
#define OFF_COL  0x00F0000   // int[E]       CSR col (src) ids
#define OFF_G    0x0710000   // overlay: gBuf (9.6MB, dead after build_k) then
                             //          bf16 G[N*128] (25.6MB)

#define CAPL   64      // LDS slots per bucket in bin_k
#define MAXNBK 200     // static LDS sizing (actual NBK=196 for N=100000)
#define CAP2   12288   // global slots per bucket (avg fill 8163, +45 sigma)

typedef short bf16x8 __attribute__((ext_vector_type(8)));
typedef float f32x4 __attribute__((ext_vector_type(4)));
typedef float f32x2 __attribute__((ext_vector_type(2)));
typedef unsigned int u32x4 __attribute__((ext_vector_type(4)));
typedef int i32x4 __attribute__((ext_vector_type(4)));

static __device__ __forceinline__ unsigned short f2bf(float f) {
    unsigned int u = __float_as_uint(f);
    u = u + 0x7fffu + ((u >> 16) & 1u);   // round-to-nearest-even
    return (unsigned short)(u >> 16);
}

// ---------- phase 0: zero gCnt + transpose/cvt W1,W2 (one dispatch) ----------
__global__ __launch_bounds__(256) void prep_k(
    const float* __restrict__ W1, const float* __restrict__ W2,
    unsigned short* __restrict__ WT1, unsigned short* __restrict__ WT2,
    int* __restrict__ gCnt, int NBK) {
    int idx = blockIdx.x * 256 + threadIdx.x;   // grid 64 -> 16384
    int n = idx >> 7, k = idx & 127;
    WT1[idx] = f2bf(W1[k * 128 + n]);
    WT2[idx] = f2bf(W2[k * 128 + n]);
    if (blockIdx.x == 0 && threadIdx.x < NBK) gCnt[threadIdx.x] = 0;
}

// ---------- phase 1: LDS-binned edge bucketing ----------
__global__ __launch_bounds__(256) void bin_k(
    const int* __restrict__ src, const int* __restrict__ dst,
    int* __restrict__ gCnt, unsigned* __restrict__ gBuf, int E, int NBK) {
    __shared__ int lcnt[MAXNBK];
    __shared__ unsigned lbuf[MAXNBK * CAPL];
    for (int i = threadIdx.x; i < NBK; i += 256) lcnt[i] = 0;
    __syncthreads();
    int base = blockIdx.x * 4096;
#pragma unroll
    for (int j = 0; j < 4; j++) {
        int e = base + j * 1024 + threadIdx.x * 4;
        int d4[4], s4[4], nv = 0;
        if (e + 3 < E) {
            i32x4 dv = *(const i32x4*)(dst + e);
            i32x4 sv = *(const i32x4*)(src + e);
#pragma unroll
            for (int q = 0; q < 4; q++) { d4[q] = dv[q]; s4[q] = sv[q]; }
            nv = 4;
        } else {
            for (int q = 0; q < 4; q++)
                if (e + q < E) { d4[nv] = dst[e + q]; s4[nv] = src[e + q]; nv++; }
        }
        for (int q = 0; q < nv; q++) {
            int d = d4[q], s = s4[q];
            int b = d >> 9;
            unsigned entry = ((unsigned)(d & 511) << 23) | (unsigned)s;
            int pos = atomicAdd(&lcnt[b], 1);
            if (pos < CAPL) {
                lbuf[b * CAPL + pos] = entry;
            } else {            // overflow spill (statistically never at CAPL=64)
                int gp = atomicAdd(&gCnt[b], 1);
                if (gp < CAP2) gBuf[(size_t)b * CAP2 + gp] = entry;
            }
        }
    }
    __syncthreads();
    for (int b = threadIdx.x; b < NBK; b += 256) {
        int n = lcnt[b]; if (n > CAPL) n = CAPL;
        if (n) {
            int gp = atomicAdd(&gCnt[b], n);
            for (int k = 0; k < n; k++) {
                int p = gp + k;
                if (p < CAP2) gBuf[(size_t)b * CAP2 + p] = lbuf[b * CAPL + k];
            }
        }
    }
}

// ---------- phase 2: per-bucket counting sort -> rp, dinv, col ----------
__global__ __launch_bounds__(256) void build_k(
    const unsigned* __restrict__ gBuf, const int* __restrict__ gCnt,
    int* __restrict__ rp, float* __restrict__ dinv, int* __restrict__ col,
    int NBK, int N) {
    __shared__ unsigned entries[CAP2];
    __shared__ int bc[256], tmp[256];
    __shared__ int ncnt[512], nrp[512], ncur[512];
    int t = threadIdx.x, b = blockIdx.x;

    // scan bucket counts -> colBase
    int c = (t < NBK) ? gCnt[t] : 0;
    if (c > CAP2) c = CAP2;
    bc[t] = c;
    tmp[t] = c;
    __syncthreads();
    for (int off = 1; off < 256; off <<= 1) {
        int x = (t >= off) ? tmp[t - off] : 0;
        __syncthreads(); tmp[t] += x; __syncthreads();
    }
    int colBase = tmp[b] - bc[b];
    int total = tmp[255];
    int cntb = bc[b];
    if (b == 0 && t == 0) rp[N] = total;

    // load this bucket's entries
    for (int k = t; k < cntb; k += 256) entries[k] = gBuf[(size_t)b * CAP2 + k];
    ncnt[t] = 0; ncnt[t + 256] = 0;
    __syncthreads();

    // pass A: per-node counts
    for (int k = t; k < cntb; k += 256) atomicAdd(&ncnt[entries[k] >> 23], 1);
    __syncthreads();

    // exclusive scan of 512 counts with 256 threads
    int v0 = ncnt[2 * t], v1 = ncnt[2 * t + 1];
    int ps = v0 + v1;
    tmp[t] = ps;
    __syncthreads();
    for (int off = 1; off < 256; off <<= 1) {
        int x = (t >= off) ? tmp[t - off] : 0;
        __syncthreads(); tmp[t] += x; __syncthreads();
    }
    int ex = tmp[t] - ps;
    nrp[2 * t] = ex;          ncur[2 * t] = ex;
    nrp[2 * t + 1] = ex + v0; ncur[2 * t + 1] = ex + v0;
    __syncthreads();

    // rp + dinv (coalesced)
    int g0 = b << 9;
    for (int i = t; i < 512; i += 256) {
        int g = g0 + i;
        if (g < N) {
            rp[g] = colBase + nrp[i];
            dinv[g] = rsqrtf((float)(ncnt[i] + 1));
        }
    }
    __syncthreads();

    // pass B: place into col (scatter confined to this bucket's region)
    for (int k = t; k < cntb; k += 256) {
        unsigned e = entries[k];
        int dl = e >> 23;
        int s = (int)(e & 0x7fffffu);
        int pos = atomicAdd(&ncur[dl], 1);
        col[colBase + pos] = s;
    }
}

// ---------- GEMM: G[r,:] = bf16( (A[r,:] @ W) * dinv[r] ) ----------
// AF32=1: A is float32 [M,lda]; AF32=0: A is bf16 (ushort) [M,lda]
// Plain cached A-loads and scalar G stores (both alternatives measured worse:
// NT loads +9us, LDS-staged coalesced epilogue +12us).
template <int AF32>
__global__ __launch_bounds__(256) void gemm_scale(
    const void* __restrict__ Av, int lda,
    const unsigned short* __restrict__ WT,
    const float* __restrict__ dinv,
    unsigned short* __restrict__ G, int M) {
    int wave = threadIdx.x >> 6;
    int lane = threadIdx.x & 63;
    int quad = lane >> 4;
    int l16  = lane & 15;
    int rowBase = blockIdx.x * 64 + wave * 16;
    int rowc = rowBase + l16;
    if (rowc > M - 1) rowc = M - 1;

    f32x4 acc[8];
#pragma unroll
    for (int t = 0; t < 8; t++) acc[t] = (f32x4){0.f, 0.f, 0.f, 0.f};

#pragma unroll
    for (int kk = 0; kk < 128; kk += 32) {
        bf16x8 a;
        if (AF32) {
            const float* Af = (const float*)Av;
            const f32x4* ap = (const f32x4*)(Af + (size_t)rowc * lda + kk + quad * 8);
            f32x4 a0 = ap[0], a1 = ap[1];
#pragma unroll
            for (int j = 0; j < 4; j++) {
                a[j]     = (short)f2bf(a0[j]);
                a[j + 4] = (short)f2bf(a1[j]);
            }
        } else {
            const unsigned short* Ab = (const unsigned short*)Av;
            a = *(const bf16x8*)(Ab + (size_t)rowc * lda + kk + quad * 8);
        }
#pragma unroll
        for (int t = 0; t < 8; t++) {
            bf16x8 b = *(const bf16x8*)(WT + (t * 16 + l16) * 128 + kk + quad * 8);
            acc[t] = __builtin_amdgcn_mfma_f32_16x16x32_bf16(a, b, acc[t], 0, 0, 0);
        }
    }
    // D layout: row = quad*4 + reg, col = l16 (within each 16x16 tile t)
#pragma unroll
    for (int r = 0; r < 4; r++) {
        int orow = rowBase + quad * 4 + r;
        if (orow < M) {
            float di = dinv[orow];
#pragma unroll
            for (int t = 0; t < 8; t++) {
                G[(size_t)orow * 128 + t * 16 + l16] = f2bf(acc[t][r] * di);
            }
        }
    }
}

// ---------- Aggregate ----------
// out[n,:] = relu(dinv[n]*(g[n,:] + sum_{s in N(n)} g[s,:]) + b)
// One wave per node. lane = 16*g + i: group g processes edge slots g, g+4,
// g+8,... (slot e0-1 = self-loop); lane loads channels [8i, 8i+8) as 16B.
// Four slots in flight per group; invalid slots clamp to the self row and
// their accumulate is predicated off. NT stores for Out. (No H1 staging:
// layer 2's GEMM reads h1 back from out[:,0:128] f32 -- bit-identical after
// f2bf, and it moves 25.6MB of writes out of this saturated kernel.)
static __device__ __forceinline__ void accum8(f32x2* acc, u32x4 v) {
#pragma unroll
    for (int d = 0; d < 4; d++) {
        f32x2 t;
        t[0] = __uint_as_float(v[d] << 16);
        t[1] = __uint_as_float(v[d] & 0xffff0000u);
        acc[d] += t;                       // v_pk_add_f32
    }
}

__global__ __launch_bounds__(256) void agg_k(
    const unsigned short* __restrict__ G,
    const int* __restrict__ rp, const int* __restrict__ col,
    const float* __restrict__ dinv, const float* __restrict__ bias,
    float* __restrict__ Out, int colbase, int N) {
    int gid = (blockIdx.x * blockDim.x + threadIdx.x) >> 6;
    if (gid >= N) return;
    int lane = threadIdx.x & 63;
    int g = lane >> 4, i = lane & 15;

    f32x2 acc[4];
#pragma unroll
    for (int j = 0; j < 4; j++) acc[j] = (f32x2){0.f, 0.f};

    int e0 = rp[gid], e1 = rp[gid + 1];
    // virtual slot list: index e0-1 == self, then col[e0..e1).
    // group g owns slots e0-1+g, +4, +8, ... ; window of 4 in flight.
    int my = e0 - 1 + g;
    int c0 = (my < e1) ? ((my >= e0) ? __builtin_nontemporal_load(col + my) : gid)
                       : -1; my += 4;
    int c1 = (my < e1) ? __builtin_nontemporal_load(col + my) : -1; my += 4;
    int c2 = (my < e1) ? __builtin_nontemporal_load(col + my) : -1; my += 4;
    int c3 = (my < e1) ? __builtin_nontemporal_load(col + my) : -1; my += 4;

    const unsigned short* Gi = G + (size_t)i * 8;

    while (c0 >= 0) {
        int n0 = (my < e1) ? __builtin_nontemporal_load(col + my) : -1; my += 4;
        int n1 = (my < e1) ? __builtin_nontemporal_load(col + my) : -1; my += 4;
        int n2 = (my < e1) ? __builtin_nontemporal_load(col + my) : -1; my += 4;
        int n3 = (my < e1) ? __builtin_nontemporal_load(col + my) : -1; my += 4;
        int a1 = (c1 >= 0) ? c1 : gid;
        int a2 = (c2 >= 0) ? c2 : gid;
        int a3 = (c3 >= 0) ? c3 : gid;
        u32x4 v0 = *(const u32x4*)(Gi + (size_t)c0 * 128);
        u32x4 v1 = *(const u32x4*)(Gi + (size_t)a1 * 128);
        u32x4 v2 = *(const u32x4*)(Gi + (size_t)a2 * 128);
        u32x4 v3 = *(const u32x4*)(Gi + (size_t)a3 * 128);
        accum8(acc, v0);
        if (c1 >= 0) accum8(acc, v1);
        if (c2 >= 0) accum8(acc, v2);
        if (c3 >= 0) accum8(acc, v3);
        c0 = n0; c1 = n1; c2 = n2; c3 = n3;
    }

    float a8[8];
#pragma unroll
    for (int d = 0; d < 4; d++) { a8[2 * d] = acc[d][0]; a8[2 * d + 1] = acc[d][1]; }
#pragma unroll
    for (int j = 0; j < 8; j++) a8[j] += __shfl_xor(a8[j], 16, 64);
#pragma unroll
    for (int j = 0; j < 8; j++) a8[j] += __shfl_xor(a8[j], 32, 64);

    if (g == 0) {
        float di = dinv[gid];
        const f32x4* bp = (const f32x4*)(bias + i * 8);
        f32x4 b0 = bp[0], b1 = bp[1];
        f32x4 o0, o1;
#pragma unroll
        for (int j = 0; j < 4; j++) {
            o0[j] = fmaxf(a8[j] * di + b0[j], 0.f);
            o1[j] = fmaxf(a8[j + 4] * di + b1[j], 0.f);
        }
        float* orow = Out + (size_t)gid * 256 + colbase + i * 8;
        __builtin_nontemporal_store(o0, (f32x4*)orow);
        __builtin_nontemporal_store(o1, (f32x4*)(orow + 4));
    }
}

extern "C" void kernel_launch(void* const* d_in, const int* in_sizes, int n_in,
                              void* d_out, int out_size, void* d_ws, size_t ws_size,
                              hipStream_t stream) {
    const float* x  = (const float*)d_in[0];   // [N,128] f32
    const float* W1 = (const float*)d_in[1];   // [128,128] f32
    const float* b1 = (const float*)d_in[2];   // [128] f32
    const float* W2 = (const float*)d_in[3];
    const float* b2 = (const float*)d_in[4];
    const int* ei = (const int*)d_in[5];       // [2,E] int32

    const int N = in_sizes[0] / 128;
    const int E = in_sizes[5] / 2;
    const int* src = ei;
    const int* dst = ei + E;
    const int NBK = (N + 511) >> 9;            // 196 for N=100000 (<= MAXNBK)

    char* ws = (char*)d_ws;
    int*      gCnt = (int*)(ws + OFF_GCNT);
    int*      rp   = (int*)(ws + OFF_RP);
    float*    dinv = (float*)(ws + OFF_DINV);
    unsigned short* WT1 = (unsigned short*)(ws + OFF_WT1);
    unsigned short* WT2 = (unsigned short*)(ws + OFF_WT2);
    int*      col  = (int*)(ws + OFF_COL);
    unsigned* gBuf = (unsigned*)(ws + OFF_G);          // dead after build_k
    unsigned short* G = (unsigned short*)(ws + OFF_G); // overlays gBuf
    float* out = (float*)d_out;

    prep_k<<<64, 256, 0, stream>>>(W1, W2, WT1, WT2, gCnt, NBK);
    bin_k<<<(E + 4095) / 4096, 256, 0, stream>>>(src, dst, gCnt, gBuf, E, NBK);
    build_k<<<NBK, 256, 0, stream>>>(gBuf, gCnt, rp, dinv, col, NBK, N);

    int gb = (N + 63) / 64;
    int ab = (N + 3) / 4;

    // Layer 1 (A = x, f32)
    gemm_scale<1><<<gb, 256, 0, stream>>>(x, 128, WT1, dinv, G, N);
    agg_k<<<ab, 256, 0, stream>>>(G, rp, col, dinv, b1, out, 0, N);
    // Layer 2 (A = h1 = out[:,0:128] f32, lda 256)
    gemm_scale<1><<<gb, 256, 0, stream>>>(out, 256, WT2, dinv, G, N);
    agg_k<<<ab, 256, 0, stream>>>(G, rp, col, dinv, b2, out, 128, N);
}

// Round 7
// 376.445 us; speedup vs baseline: 1.0485x; 1.0029x over previous
//
#include <hip/hip_runtime.h>
#include <hip/hip_bf16.h>

// GCN encoder: out = concat(h1, h2), h_l = relu(Dinv(A+I)Dinv (x@W_l) + b_l)
// Inputs: x[N,128], W1,W2[128,128], b1,b2[128] = float32; edge_index int32 [2,E]
// Output: float32 [N,256] (harness compares vs bf16-emulated np ref, 2% rel).
//
// Round 12: permuted-G layout. gemm's epilogue was 32 scalar 2B stores/thread
// at 32B lane-stride (64 scattered sectors per wave-instruction). Storing G
// with column permutation p(c) = (c&15)*8 + (c>>4) makes each MFMA lane's 8
// values CONTIGUOUS: 4x bf16x8 coalesced stores (256B/row), zero extra ops.
// agg's row-gather+sum is position-agnostic (unchanged); agg's epilogue
// un-permutes via a 512B intra-wave LDS transpose (no barrier) before the
// channel-contiguous out write. Legal because G's only consumers are agg
// (opaque columns) -- H1 is gone and gemm2 reads channel-space `out`.
// Everything else identical to round 11 (the 377.5us session best).
//
// ws layout (bytes):
#define OFF_GCNT 0x0000000   // int[196]     bucket cursors (zeroed by prep_k)
#define OFF_RP   0x0001000   // int[N+1]     CSR row pointers
#define OFF_DINV 0x0070000   // float[N]     rsqrt(deg+1)
#define OFF_WT1  0x00E0000   // bf16[128*128] W1^T
#define OFF_WT2  0x00E8000   // bf16[128*128] W2^T
#define OFF_COL  0x00F0000   // int[E]       CSR col (src) ids
#define OFF_G    0x0710000   // overlay: gBuf (9.6MB, dead after build_k) then
                             //          bf16 G[N*128] (25.6MB, PERMUTED cols)

#define CAPL   64      // LDS slots per bucket in bin_k
#define MAXNBK 200     // static LDS sizing (actual NBK=196 for N=100000)
#define CAP2   12288   // global slots per bucket (avg fill 8163, +45 sigma)

typedef short bf16x8 __attribute__((ext_vector_type(8)));
typedef float f32x4 __attribute__((ext_vector_type(4)));
typedef float f32x2 __attribute__((ext_vector_type(2)));
typedef unsigned int u32x4 __attribute__((ext_vector_type(4)));
typedef int i32x4 __attribute__((ext_vector_type(4)));

static __device__ __forceinline__ unsigned short f2bf(float f) {
    unsigned int u = __float_as_uint(f);
    u = u + 0x7fffu + ((u >> 16) & 1u);   // round-to-nearest-even
    return (unsigned short)(u >> 16);
}

// ---------- phase 0: zero gCnt + transpose/cvt W1,W2 (one dispatch) ----------
__global__ __launch_bounds__(256) void prep_k(
    const float* __restrict__ W1, const float* __restrict__ W2,
    unsigned short* __restrict__ WT1, unsigned short* __restrict__ WT2,
    int* __restrict__ gCnt, int NBK) {
    int idx = blockIdx.x * 256 + threadIdx.x;   // grid 64 -> 16384
    int n = idx >> 7, k = idx & 127;
    WT1[idx] = f2bf(W1[k * 128 + n]);
    WT2[idx] = f2bf(W2[k * 128 + n]);
    if (blockIdx.x == 0 && threadIdx.x < NBK) gCnt[threadIdx.x] = 0;
}

// ---------- phase 1: LDS-binned edge bucketing ----------
__global__ __launch_bounds__(256) void bin_k(
    const int* __restrict__ src, const int* __restrict__ dst,
    int* __restrict__ gCnt, unsigned* __restrict__ gBuf, int E, int NBK) {
    __shared__ int lcnt[MAXNBK];
    __shared__ unsigned lbuf[MAXNBK * CAPL];
    for (int i = threadIdx.x; i < NBK; i += 256) lcnt[i] = 0;
    __syncthreads();
    int base = blockIdx.x * 4096;
#pragma unroll
    for (int j = 0; j < 4; j++) {
        int e = base + j * 1024 + threadIdx.x * 4;
        int d4[4], s4[4], nv = 0;
        if (e + 3 < E) {
            i32x4 dv = *(const i32x4*)(dst + e);
            i32x4 sv = *(const i32x4*)(src + e);
#pragma unroll
            for (int q = 0; q < 4; q++) { d4[q] = dv[q]; s4[q] = sv[q]; }
            nv = 4;
        } else {
            for (int q = 0; q < 4; q++)
                if (e + q < E) { d4[nv] = dst[e + q]; s4[nv] = src[e + q]; nv++; }
        }
        for (int q = 0; q < nv; q++) {
            int d = d4[q], s = s4[q];
            int b = d >> 9;
            unsigned entry = ((unsigned)(d & 511) << 23) | (unsigned)s;
            int pos = atomicAdd(&lcnt[b], 1);
            if (pos < CAPL) {
                lbuf[b * CAPL + pos] = entry;
            } else {            // overflow spill (statistically never at CAPL=64)
                int gp = atomicAdd(&gCnt[b], 1);
                if (gp < CAP2) gBuf[(size_t)b * CAP2 + gp] = entry;
            }
        }
    }
    __syncthreads();
    for (int b = threadIdx.x; b < NBK; b += 256) {
        int n = lcnt[b]; if (n > CAPL) n = CAPL;
        if (n) {
            int gp = atomicAdd(&gCnt[b], n);
            for (int k = 0; k < n; k++) {
                int p = gp + k;
                if (p < CAP2) gBuf[(size_t)b * CAP2 + p] = lbuf[b * CAPL + k];
            }
        }
    }
}

// ---------- phase 2: per-bucket counting sort -> rp, dinv, col ----------
__global__ __launch_bounds__(256) void build_k(
    const unsigned* __restrict__ gBuf, const int* __restrict__ gCnt,
    int* __restrict__ rp, float* __restrict__ dinv, int* __restrict__ col,
    int NBK, int N) {
    __shared__ unsigned entries[CAP2];
    __shared__ int bc[256], tmp[256];
    __shared__ int ncnt[512], nrp[512], ncur[512];
    int t = threadIdx.x, b = blockIdx.x;

    // scan bucket counts -> colBase
    int c = (t < NBK) ? gCnt[t] : 0;
    if (c > CAP2) c = CAP2;
    bc[t] = c;
    tmp[t] = c;
    __syncthreads();
    for (int off = 1; off < 256; off <<= 1) {
        int x = (t >= off) ? tmp[t - off] : 0;
        __syncthreads(); tmp[t] += x; __syncthreads();
    }
    int colBase = tmp[b] - bc[b];
    int total = tmp[255];
    int cntb = bc[b];
    if (b == 0 && t == 0) rp[N] = total;

    // load this bucket's entries
    for (int k = t; k < cntb; k += 256) entries[k] = gBuf[(size_t)b * CAP2 + k];
    ncnt[t] = 0; ncnt[t + 256] = 0;
    __syncthreads();

    // pass A: per-node counts
    for (int k = t; k < cntb; k += 256) atomicAdd(&ncnt[entries[k] >> 23], 1);
    __syncthreads();

    // exclusive scan of 512 counts with 256 threads
    int v0 = ncnt[2 * t], v1 = ncnt[2 * t + 1];
    int ps = v0 + v1;
    tmp[t] = ps;
    __syncthreads();
    for (int off = 1; off < 256; off <<= 1) {
        int x = (t >= off) ? tmp[t - off] : 0;
        __syncthreads(); tmp[t] += x; __syncthreads();
    }
    int ex = tmp[t] - ps;
    nrp[2 * t] = ex;          ncur[2 * t] = ex;
    nrp[2 * t + 1] = ex + v0; ncur[2 * t + 1] = ex + v0;
    __syncthreads();

    // rp + dinv (coalesced)
    int g0 = b << 9;
    for (int i = t; i < 512; i += 256) {
        int g = g0 + i;
        if (g < N) {
            rp[g] = colBase + nrp[i];
            dinv[g] = rsqrtf((float)(ncnt[i] + 1));
        }
    }
    __syncthreads();

    // pass B: place into col (scatter confined to this bucket's region)
    for (int k = t; k < cntb; k += 256) {
        unsigned e = entries[k];
        int dl = e >> 23;
        int s = (int)(e & 0x7fffffu);
        int pos = atomicAdd(&ncur[dl], 1);
        col[colBase + pos] = s;
    }
}

// ---------- GEMM: G[r, p(:)] = bf16( (A[r,:] @ W) * dinv[r] ) ----------
// AF32=1: A is float32 [M,lda]; AF32=0: A is bf16 (ushort) [M,lda]
// G stored with column permutation p(c) = (c&15)*8 + (c>>4): lane l16's 8
// MFMA outputs (channels t*16+l16, t=0..7) become positions [8*l16, 8*l16+8)
// -> one contiguous bf16x8 store per r; 16 lanes cover 256B/row coalesced.
template <int AF32>
__global__ __launch_bounds__(256) void gemm_scale(
    const void* __restrict__ Av, int lda,
    const unsigned short* __restrict__ WT,
    const float* __restrict__ dinv,
    unsigned short* __restrict__ G, int M) {
    int wave = threadIdx.x >> 6;
    int lane = threadIdx.x & 63;
    int quad = lane >> 4;
    int l16  = lane & 15;
    int rowBase = blockIdx.x * 64 + wave * 16;
    int rowc = rowBase + l16;
    if (rowc > M - 1) rowc = M - 1;

    f32x4 acc[8];
#pragma unroll
    for (int t = 0; t < 8; t++) acc[t] = (f32x4){0.f, 0.f, 0.f, 0.f};

#pragma unroll
    for (int kk = 0; kk < 128; kk += 32) {
        bf16x8 a;
        if (AF32) {
            const float* Af = (const float*)Av;
            const f32x4* ap = (const f32x4*)(Af + (size_t)rowc * lda + kk + quad * 8);
            f32x4 a0 = ap[0], a1 = ap[1];
#pragma unroll
            for (int j = 0; j < 4; j++) {
                a[j]     = (short)f2bf(a0[j]);
                a[j + 4] = (short)f2bf(a1[j]);
            }
        } else {
            const unsigned short* Ab = (const unsigned short*)Av;
            a = *(const bf16x8*)(Ab + (size_t)rowc * lda + kk + quad * 8);
        }
#pragma unroll
        for (int t = 0; t < 8; t++) {
            bf16x8 b = *(const bf16x8*)(WT + (t * 16 + l16) * 128 + kk + quad * 8);
            acc[t] = __builtin_amdgcn_mfma_f32_16x16x32_bf16(a, b, acc[t], 0, 0, 0);
        }
    }
    // D layout: row = quad*4 + r, channel = t*16 + l16 -> position l16*8 + t.
#pragma unroll
    for (int r = 0; r < 4; r++) {
        int orow = rowBase + quad * 4 + r;
        if (orow < M) {
            float di = dinv[orow];
            bf16x8 v;
#pragma unroll
            for (int t = 0; t < 8; t++) v[t] = (short)f2bf(acc[t][r] * di);
            *(bf16x8*)(G + (size_t)orow * 128 + l16 * 8) = v;
        }
    }
}

// ---------- Aggregate ----------
// out[n,:] = relu(dinv[n]*(g[n,:] + sum_{s in N(n)} g[s,:]) + b)
// One wave per node. lane = 16*g + i: group g processes edge slots g, g+4,
// g+8,... (slot e0-1 = self-loop); lane loads G positions [8i,8i+8) as 16B.
// G columns are PERMUTED (position p holds channel (p&7)*16 + (p>>3)); the
// gather+sum is elementwise so unchanged. Epilogue un-permutes via a 512B
// intra-wave LDS transpose (no barrier: same-wave ds ordering via lgkmcnt),
// then bias/relu/NT-store channel-contiguous f32.
static __device__ __forceinline__ void accum8(f32x2* acc, u32x4 v) {
#pragma unroll
    for (int d = 0; d < 4; d++) {
        f32x2 t;
        t[0] = __uint_as_float(v[d] << 16);
        t[1] = __uint_as_float(v[d] & 0xffff0000u);
        acc[d] += t;                       // v_pk_add_f32
    }
}

__global__ __launch_bounds__(256) void agg_k(
    const unsigned short* __restrict__ G,
    const int* __restrict__ rp, const int* __restrict__ col,
    const float* __restrict__ dinv, const float* __restrict__ bias,
    float* __restrict__ Out, int colbase, int N) {
    __shared__ float stage[4][128];        // per-wave un-permute scratch
    int gid = (blockIdx.x * blockDim.x + threadIdx.x) >> 6;
    if (gid >= N) return;
    int wave = threadIdx.x >> 6;
    int lane = threadIdx.x & 63;
    int g = lane >> 4, i = lane & 15;

    f32x2 acc[4];
#pragma unroll
    for (int j = 0; j < 4; j++) acc[j] = (f32x2){0.f, 0.f};

    int e0 = rp[gid], e1 = rp[gid + 1];
    // virtual slot list: index e0-1 == self, then col[e0..e1).
    // group g owns slots e0-1+g, +4, +8, ... ; window of 4 in flight.
    int my = e0 - 1 + g;
    int c0 = (my < e1) ? ((my >= e0) ? __builtin_nontemporal_load(col + my) : gid)
                       : -1; my += 4;
    int c1 = (my < e1) ? __builtin_nontemporal_load(col + my) : -1; my += 4;
    int c2 = (my < e1) ? __builtin_nontemporal_load(col + my) : -1; my += 4;
    int c3 = (my < e1) ? __builtin_nontemporal_load(col + my) : -1; my += 4;

    const unsigned short* Gi = G + (size_t)i * 8;

    while (c0 >= 0) {
        int n0 = (my < e1) ? __builtin_nontemporal_load(col + my) : -1; my += 4;
        int n1 = (my < e1) ? __builtin_nontemporal_load(col + my) : -1; my += 4;
        int n2 = (my < e1) ? __builtin_nontemporal_load(col + my) : -1; my += 4;
        int n3 = (my < e1) ? __builtin_nontemporal_load(col + my) : -1; my += 4;
        int a1 = (c1 >= 0) ? c1 : gid;
        int a2 = (c2 >= 0) ? c2 : gid;
        int a3 = (c3 >= 0) ? c3 : gid;
        u32x4 v0 = *(const u32x4*)(Gi + (size_t)c0 * 128);
        u32x4 v1 = *(const u32x4*)(Gi + (size_t)a1 * 128);
        u32x4 v2 = *(const u32x4*)(Gi + (size_t)a2 * 128);
        u32x4 v3 = *(const u32x4*)(Gi + (size_t)a3 * 128);
        accum8(acc, v0);
        if (c1 >= 0) accum8(acc, v1);
        if (c2 >= 0) accum8(acc, v2);
        if (c3 >= 0) accum8(acc, v3);
        c0 = n0; c1 = n1; c2 = n2; c3 = n3;
    }

    // combine the 4 groups (butterfly leaves the full sum in every lane)
    float a8[8];
#pragma unroll
    for (int d = 0; d < 4; d++) { a8[2 * d] = acc[d][0]; a8[2 * d + 1] = acc[d][1]; }
#pragma unroll
    for (int j = 0; j < 8; j++) a8[j] += __shfl_xor(a8[j], 16, 64);
#pragma unroll
    for (int j = 0; j < 8; j++) a8[j] += __shfl_xor(a8[j], 32, 64);

    if (g == 0) {
        // a8[j] = position 8i+j = channel j*16+i. Un-permute via LDS.
#pragma unroll
        for (int j = 0; j < 8; j++) stage[wave][j * 16 + i] = a8[j];
        // same-wave ds write->read: compiler orders via lgkmcnt, no barrier
        f32x4 s0 = *(const f32x4*)&stage[wave][i * 8];
        f32x4 s1 = *(const f32x4*)&stage[wave][i * 8 + 4];
        float di = dinv[gid];
        const f32x4* bp = (const f32x4*)(bias + i * 8);
        f32x4 b0 = bp[0], b1 = bp[1];
        f32x4 o0, o1;
#pragma unroll
        for (int j = 0; j < 4; j++) {
            o0[j] = fmaxf(s0[j] * di + b0[j], 0.f);
            o1[j] = fmaxf(s1[j] * di + b1[j], 0.f);
        }
        float* orow = Out + (size_t)gid * 256 + colbase + i * 8;
        __builtin_nontemporal_store(o0, (f32x4*)orow);
        __builtin_nontemporal_store(o1, (f32x4*)(orow + 4));
    }
}

extern "C" void kernel_launch(void* const* d_in, const int* in_sizes, int n_in,
                              void* d_out, int out_size, void* d_ws, size_t ws_size,
                              hipStream_t stream) {
    const float* x  = (const float*)d_in[0];   // [N,128] f32
    const float* W1 = (const float*)d_in[1];   // [128,128] f32
    const float* b1 = (const float*)d_in[2];   // [128] f32
    const float* W2 = (const float*)d_in[3];
    const float* b2 = (const float*)d_in[4];
    const int* ei = (const int*)d_in[5];       // [2,E] int32

    const int N = in_sizes[0] / 128;
    const int E = in_sizes[5] / 2;
    const int* src = ei;
    const int* dst = ei + E;
    const int NBK = (N + 511) >> 9;            // 196 for N=100000 (<= MAXNBK)

    char* ws = (char*)d_ws;
    int*      gCnt = (int*)(ws + OFF_GCNT);
    int*      rp   = (int*)(ws + OFF_RP);
    float*    dinv = (float*)(ws + OFF_DINV);
    unsigned short* WT1 = (unsigned short*)(ws + OFF_WT1);
    unsigned short* WT2 = (unsigned short*)(ws + OFF_WT2);
    int*      col  = (int*)(ws + OFF_COL);
    unsigned* gBuf = (unsigned*)(ws + OFF_G);          // dead after build_k
    unsigned short* G = (unsigned short*)(ws + OFF_G); // overlays gBuf
    float* out = (float*)d_out;

    prep_k<<<64, 256, 0, stream>>>(W1, W2, WT1, WT2, gCnt, NBK);
    bin_k<<<(E + 4095) / 4096, 256, 0, stream>>>(src, dst, gCnt, gBuf, E, NBK);
    build_k<<<NBK, 256, 0, stream>>>(gBuf, gCnt, rp, dinv, col, NBK, N);

    int gb = (N + 63) / 64;
    int ab = (N + 3) / 4;

    // Layer 1 (A = x, f32)
    gemm_scale<1><<<gb, 256, 0, stream>>>(x, 128, WT1, dinv, G, N);
    agg_k<<<ab, 256, 0, stream>>>(G, rp, col, dinv, b1, out, 0, N);
    // Layer 2 (A = h1 = out[:,0:128] f32, lda 256)
    gemm_scale<1><<<gb, 256, 0, stream>>>(out, 256, WT2, dinv, G, N);
    agg_k<<<ab, 256, 0, stream>>>(G, rp, col, dinv, b2, out, 128, N);
}